// Round 6
// baseline (573.616 us; speedup 1.0000x reference)
//
#include <hip/hip_runtime.h>
#include <cstdint>
#include <cstddef>

// PCFG inside algorithm. B=8, n=28, NT=32, T=64, ST=96.
// DP state kept exp-normalized: eB_g[b][lvl][pos][sym] = exp(beta - bmax),
// bmax_g[b][lvl][pos]. Terminal exp table elT_g precomputed once.
// Step kernel: grid (nc, B), 512 threads. Block (b,ch) owns 512 pair-columns
// of the packed erule table in REGISTERS (8 float4/thread). 4 barriers/step.
// Finalize of level w-1 (partials reduce + normalize + bmax) fused into step
// w's phase A, redundantly per block (bitwise identical). Partials/M ping-pong.
// Quadrants: w==1: TT (8 chunks); w>=2: TN(ch0-3) NT(ch4-7) NN(ch8-9, w>=3).

#define NMAX 28

// LDS float offsets
#define O_ELT 0        // 64*29
#define O_BW1 1856     // 32*30 (level w-1, freshly finalized)
#define O_ELN 2816     // 5888: slot k-1 (k=1..w-2): left level k, [sym][s] pitch SP
#define O_ERN 8704     // 5888: slot k-1: right level w-1-k shifted, [sym][s] pitch SP
#define O_BMX 14592    // 28*28: bmax rows [lvl][pos]
#define O_G   15376    // 28*28: g[k][s]
#define O_MSP 16160    // 32
#define O_NUM 16192    // 27*516
#define LDSF  30124
// red[g16][s*32+a] (16*896=14336) aliases offset 0 (tables dead by then)

__global__ __launch_bounds__(256) void mrule_kernel(const float* __restrict__ rule,
                                                    float* __restrict__ mrule) {
    int a = blockIdx.x, b = blockIdx.y, tid = threadIdx.x;
    const float* base = rule + (size_t)(b * 32 + a) * 9216;
    float v = -3.0e38f;
    for (int i = tid; i < 9216; i += 256) v = fmaxf(v, base[i]);
    for (int off = 32; off > 0; off >>= 1) v = fmaxf(v, __shfl_xor(v, off, 64));
    __shared__ float red[4];
    if ((tid & 63) == 0) red[tid >> 6] = v;
    __syncthreads();
    if (tid == 0)
        mrule[b * 32 + a] = fmaxf(fmaxf(red[0], red[1]), fmaxf(red[2], red[3]));
}

__global__ __launch_bounds__(256) void pack_kernel(const float* __restrict__ rule,
                                                   const float* __restrict__ mrule,
                                                   float* __restrict__ E_TT,
                                                   float* __restrict__ E_TN,
                                                   float* __restrict__ E_NT,
                                                   float* __restrict__ E_NN) {
    int b = blockIdx.y, tid = threadIdx.x;
    int a = tid & 31;
    int cc = blockIdx.x * 8 + (tid >> 5); // 0..2303
    float mr = mrule[b * 32 + a];
    int l, r;
    float* dst;
    if (cc < 1024) {
        int flat = cc * 4;
        l = 32 + (flat >> 6); r = 32 + (flat & 63);
        dst = E_TT + ((size_t)(b * 1024 + cc) * 32 + a) * 4;
    } else if (cc < 1536) {
        int flat = (cc - 1024) * 4;
        l = 32 + (flat >> 5); r = flat & 31;
        dst = E_TN + ((size_t)(b * 512 + (cc - 1024)) * 32 + a) * 4;
    } else if (cc < 2048) {
        int flat = (cc - 1536) * 4;
        l = flat >> 6; r = 32 + (flat & 63);
        dst = E_NT + ((size_t)(b * 512 + (cc - 1536)) * 32 + a) * 4;
    } else {
        int flat = (cc - 2048) * 4;
        l = flat >> 5; r = flat & 31;
        dst = E_NN + ((size_t)(b * 256 + (cc - 2048)) * 32 + a) * 4;
    }
    const float4 v = *(const float4*)(rule + (((size_t)(b * 32 + a) * 96 + l) * 96 + r));
    float4 o;
    o.x = expf(v.x - mr); o.y = expf(v.y - mr);
    o.z = expf(v.z - mr); o.w = expf(v.w - mr);
    *(float4*)dst = o;
}

// ---- prep: elT_g = exp(unary - bmax0), bmax_g row 0, emrule ----
__global__ __launch_bounds__(256) void prep_kernel(const float* __restrict__ unary,
                                                   const float* __restrict__ mrule,
                                                   float* __restrict__ elT_g,
                                                   float* __restrict__ bmax_g,
                                                   float* __restrict__ emrule, int n) {
    int b = blockIdx.x, tid = threadIdx.x;
    if (tid < 32) emrule[b * 32 + tid] = expf(mrule[b * 32 + tid]);
    for (int pos = tid >> 6; pos < n; pos += 4) {
        int t = tid & 63;
        float v = unary[((size_t)(b * n) + pos) * 64 + t];
        float m = v;
        for (int off = 32; off > 0; off >>= 1) m = fmaxf(m, __shfl_xor(m, off, 64));
        elT_g[((size_t)(b * n) + pos) * 64 + t] = expf(v - m);
        if (t == 0) bmax_g[((size_t)b * n + 0) * n + pos] = m;
    }
}

__global__ __launch_bounds__(512) void step_kernel(
    const float* __restrict__ elT_g, const float* __restrict__ emrule,
    float* __restrict__ bmax_g, float* __restrict__ eB_g,
    const float* __restrict__ E_TT, const float* __restrict__ E_TN,
    const float* __restrict__ E_NT, const float* __restrict__ E_NN,
    const float* __restrict__ pin, float* __restrict__ pout,
    const float* __restrict__ Min, float* __restrict__ Mout,
    int w, int n) {
    extern __shared__ float lds[];
    const int b = blockIdx.y, ch = blockIdx.x, tid = threadIdx.x;
    const int S = n - w, SP = S | 1;
    const int a = tid & 31, g16 = tid >> 5;

    // ---- quadrant select + E register loads (issued first) ----
    int quad, base128;
    const float4* Eq;
    if (w == 1)      { quad = 0; base128 = ch * 128;       Eq = (const float4*)E_TT + (size_t)b * 32768; }
    else if (ch < 4) { quad = 1; base128 = ch * 128;       Eq = (const float4*)E_TN + (size_t)b * 16384; }
    else if (ch < 8) { quad = 2; base128 = (ch - 4) * 128; Eq = (const float4*)E_NT + (size_t)b * 16384; }
    else             { quad = 3; base128 = (ch - 8) * 128; Eq = (const float4*)E_NN + (size_t)b * 8192;  }
    float4 e4[8];
    #pragma unroll
    for (int i = 0; i < 8; ++i)
        e4[i] = Eq[(size_t)(base128 + g16 * 8 + i) * 32 + a];

    // ---- phase A (all independent): stage elT, bmax rows, eB tables; finalize ----
    for (int idx = tid; idx < n * 64; idx += 512) {
        int pos = idx >> 6, t = idx & 63;
        lds[O_ELT + t * 29 + pos] = elT_g[((size_t)b * n + pos) * 64 + t];
    }
    {
        int hi = (w == 1) ? 1 : (w - 1);   // rows [0,hi) from global
        for (int idx = tid; idx < hi * 32; idx += 512) {
            int k = idx >> 5, pos = idx & 31;
            if (pos < n)
                lds[O_BMX + k * NMAX + pos] = bmax_g[((size_t)b * n + k) * n + pos];
        }
    }
    for (int kk = 1; kk <= w - 2; ++kk) {
        const float* rowL = eB_g + (((size_t)b * n + kk) * n) * 32;
        const float* rowR = eB_g + (((size_t)b * n + (w - 1 - kk)) * n) * 32;
        for (int idx = tid; idx < S * 32; idx += 512) {
            int s = idx >> 5, sym = idx & 31;
            lds[O_ELN + (kk - 1) * 32 * SP + sym * SP + s] = rowL[s * 32 + sym];
            lds[O_ERN + (kk - 1) * 32 * SP + sym * SP + s] = rowR[(s + kk + 1) * 32 + sym];
        }
    }
    if (w >= 2) {
        const int wp = w - 1, Sp = S + 1;
        const int CHp = (wp >= 3) ? 10 : 8;
        const float* pb = pin + (size_t)b * (10 * 864);
        for (int e = tid; e < Sp * 32; e += 512) {
            float t = 0.f;
            #pragma unroll
            for (int c = 0; c < 8; ++c) t += pb[c * 864 + e];
            if (CHp == 10) t += pb[8 * 864 + e] + pb[9 * 864 + e];
            int s = e >> 5, aa = e & 31;
            float t2 = t * emrule[b * 32 + aa];
            float m2 = t2;
            for (int off = 16; off > 0; off >>= 1)
                m2 = fmaxf(m2, __shfl_xor(m2, off, 32));
            float eB = t2 / m2;
            eB_g[(((size_t)b * n + wp) * n + s) * 32 + aa] = eB;
            lds[O_BW1 + aa * 30 + s] = eB;
            if (aa == 0) {
                float bm = logf(m2) + Min[b * NMAX + s];
                lds[O_BMX + wp * NMAX + s] = bm;
                bmax_g[((size_t)b * n + wp) * n + s] = bm;
            }
        }
    }
    __syncthreads();

    // ---- phase B: Mspan + g[k][s] ----
    if (tid < S) {
        int s = tid;
        float M = -3.0e38f;
        for (int k = 0; k < w; ++k)
            M = fmaxf(M, lds[O_BMX + k * NMAX + s] +
                          lds[O_BMX + (w - 1 - k) * NMAX + s + k + 1]);
        lds[O_MSP + s] = M;
        for (int k = 0; k < w; ++k)
            lds[O_G + k * NMAX + s] =
                expf(lds[O_BMX + k * NMAX + s] +
                     lds[O_BMX + (w - 1 - k) * NMAX + s + k + 1] - M);
    }
    __syncthreads();

    // ---- phase C: numer build (this chunk's 512 pair-cols, all spans) ----
    {
        const int cL = tid;
        int l, r;
        if (quad == 0)      { int cc = ch * 512 + cL;       l = cc >> 6; r = cc & 63; }
        else if (quad == 1) { int cc = ch * 512 + cL;       l = cc >> 5; r = cc & 31; }
        else if (quad == 2) { int cc = (ch - 4) * 512 + cL; l = cc >> 6; r = cc & 63; }
        else                { int cc = (ch - 8) * 512 + cL; l = cc >> 5; r = cc & 31; }
        for (int s = 0; s < S; ++s) {
            float v;
            if (quad == 0)
                v = lds[O_ELT + l * 29 + s] * lds[O_ELT + r * 29 + (s + 1)] *
                    lds[O_G + s];
            else if (quad == 1)
                v = lds[O_ELT + l * 29 + s] * lds[O_BW1 + r * 30 + (s + 1)] *
                    lds[O_G + s];
            else if (quad == 2)
                v = lds[O_BW1 + l * 30 + s] * lds[O_ELT + r * 29 + (s + w)] *
                    lds[O_G + (w - 1) * NMAX + s];
            else {
                float acc = 0.f;
                for (int k = 1; k <= w - 2; ++k)
                    acc = fmaf(lds[O_ELN + (k - 1) * 32 * SP + l * SP + s],
                               lds[O_ERN + (k - 1) * 32 * SP + r * SP + s] *
                                   lds[O_G + k * NMAX + s],
                               acc);
                v = acc;
            }
            lds[O_NUM + s * 516 + cL] = v;
        }
    }
    __syncthreads();

    // ---- phase D: contraction (E regs x numer broadcast) -> red (aliases tables) ----
    for (int s = 0; s < S; ++s) {
        float acc = 0.f;
        #pragma unroll
        for (int i = 0; i < 8; ++i) {
            float4 nv = *(const float4*)&lds[O_NUM + s * 516 + g16 * 32 + i * 4];
            float4 t = e4[i];
            acc = fmaf(nv.x, t.x, fmaf(nv.y, t.y, fmaf(nv.z, t.z, fmaf(nv.w, t.w, acc))));
        }
        lds[g16 * 896 + s * 32 + a] = acc;
    }
    __syncthreads();

    // ---- phase E: reduce groups -> chunk partials + M ----
    {
        float* pb = pout + (size_t)b * (10 * 864);
        for (int e = tid; e < S * 32; e += 512) {
            float t = 0.f;
            #pragma unroll
            for (int g2 = 0; g2 < 16; ++g2) t += lds[g2 * 896 + e];
            pb[ch * 864 + e] = t;
        }
        if (tid < S) Mout[b * NMAX + tid] = lds[O_MSP + tid];
    }
}

// ---- final: reduce level n-1 span-0 partials, add root, logsumexp ----
__global__ void final_kernel(const float* __restrict__ pin,
                             const float* __restrict__ Min,
                             const float* __restrict__ mrule,
                             const float* __restrict__ root,
                             float* __restrict__ out, int n) {
    int b = blockIdx.x, a = threadIdx.x; // 32 threads
    int CHp = ((n - 1) >= 3) ? 10 : 8;
    const float* pb = pin + (size_t)b * (10 * 864);
    float t = 0.f;
    for (int c = 0; c < CHp; ++c) t += pb[c * 864 + a];
    float v = logf(t) + Min[b * NMAX] + mrule[b * 32 + a] + root[b * 32 + a];
    float m = v;
    for (int off = 16; off > 0; off >>= 1) m = fmaxf(m, __shfl_xor(m, off, 32));
    float e = expf(v - m);
    for (int off = 16; off > 0; off >>= 1) e += __shfl_xor(e, off, 32);
    if (a == 0) out[b] = m + logf(e);
}

extern "C" void kernel_launch(void* const* d_in, const int* in_sizes, int n_in,
                              void* d_out, int out_size, void* d_ws, size_t ws_size,
                              hipStream_t stream) {
    const float* unary = (const float*)d_in[0]; // B,n,64
    const float* rule  = (const float*)d_in[1]; // B,32,96,96
    const float* root  = (const float*)d_in[2]; // B,32
    float* out = (float*)d_out;

    const int B = in_sizes[2] / 32;
    int n = in_sizes[0] / (B * 64);

    float* ws = (float*)d_ws;
    float* mrule  = ws;                               // B*32
    float* emrule = mrule + (size_t)B * 32;           // B*32
    float* bmax_g = emrule + (size_t)B * 32;          // B*n*n
    float* eB_g   = bmax_g + (size_t)B * n * n;       // B*n*n*32
    float* elT_g  = eB_g + (size_t)B * n * n * 32;    // B*n*64
    float* E_TT   = elT_g + (size_t)B * n * 64;       // B*1024*32*4
    float* E_TN   = E_TT + (size_t)B * 131072;        // B*512*32*4
    float* E_NT   = E_TN + (size_t)B * 65536;         // B*512*32*4
    float* E_NN   = E_NT + (size_t)B * 65536;         // B*256*32*4
    float* partA  = E_NN + (size_t)B * 32768;         // B*10*864
    float* partB  = partA + (size_t)B * 10 * 864;
    float* MbufA  = partB + (size_t)B * 10 * 864;     // B*28
    float* MbufB  = MbufA + (size_t)B * NMAX;

    mrule_kernel<<<dim3(32, B), 256, 0, stream>>>(rule, mrule);
    pack_kernel<<<dim3(288, B), 256, 0, stream>>>(rule, mrule, E_TT, E_TN, E_NT, E_NN);
    prep_kernel<<<dim3(B), 256, 0, stream>>>(unary, mrule, elT_g, bmax_g, emrule, n);

    hipFuncSetAttribute((const void*)step_kernel,
                        hipFuncAttributeMaxDynamicSharedMemorySize, LDSF * 4);

    float* pbuf[2] = { partA, partB };
    float* mbuf[2] = { MbufA, MbufB };
    for (int w = 1; w < n; ++w) {
        int nc = (w >= 3) ? 10 : 8;
        step_kernel<<<dim3(nc, B), 512, LDSF * 4, stream>>>(
            elT_g, emrule, bmax_g, eB_g, E_TT, E_TN, E_NT, E_NN,
            pbuf[1 - (w & 1)], pbuf[w & 1], mbuf[1 - (w & 1)], mbuf[w & 1], w, n);
    }
    final_kernel<<<dim3(B), 32, 0, stream>>>(pbuf[(n - 1) & 1], mbuf[(n - 1) & 1],
                                             mrule, root, out, n);
}